// Round 6
// baseline (2994.374 us; speedup 1.0000x reference)
//
#include <hip/hip_runtime.h>
#include <cfloat>
#include <cmath>

#define D 128
#define D4 32    // D/4 float4s per row
#define CH 8     // channel passes for the gather
#define CPP 16   // channels per pass (D/CH)

// ---------- helpers ----------
__device__ __forceinline__ float4 f4fma(float s, float4 a, float4 acc) {
    acc.x = fmaf(s, a.x, acc.x);
    acc.y = fmaf(s, a.y, acc.y);
    acc.z = fmaf(s, a.z, acc.z);
    acc.w = fmaf(s, a.w, acc.w);
    return acc;
}

// ---------- degree count (int) ----------
__global__ void k_count(const int* __restrict__ dst, int* __restrict__ cnt, int E) {
    int i = blockIdx.x * blockDim.x + threadIdx.x;
    if (i < E) atomicAdd(&cnt[dst[i]], 1);
}

__global__ void k_dinv(const int* __restrict__ cnt, float* __restrict__ dinv, int N) {
    int i = blockIdx.x * blockDim.x + threadIdx.x;
    if (i < N) dinv[i] = 1.0f / sqrtf((float)cnt[i] + 1.0f);  // +1 = self-loop
}

// ---------- exclusive scan of cnt -> rowptr (single block, 1024 thr) ----------
__global__ __launch_bounds__(1024)
void k_scan(const int* __restrict__ cnt, int* __restrict__ rowptr,
            int* __restrict__ cur, int N) {
    __shared__ int part[1024];
    int t = threadIdx.x;
    int chunk = (N + 1023) / 1024;
    int begin = t * chunk;
    int end = begin + chunk; if (end > N) end = N;
    int s = 0;
    for (int i = begin; i < end; ++i) s += cnt[i];
    part[t] = s;
    __syncthreads();
    for (int off = 1; off < 1024; off <<= 1) {
        int v = (t >= off) ? part[t - off] : 0;
        __syncthreads();
        part[t] += v;
        __syncthreads();
    }
    int run = (t == 0) ? 0 : part[t - 1];
    for (int i = begin; i < end; ++i) {
        rowptr[i] = run; cur[i] = run;
        run += cnt[i];
    }
    if (t == 1023) rowptr[N] = part[1023];
}

// ---------- fill CSR edge data: (src, norm) sorted by dst ----------
__global__ void k_fill(const int* __restrict__ src, const int* __restrict__ dst,
                       const float* __restrict__ dinv, int* __restrict__ cur,
                       int2* __restrict__ edata, int E) {
    int e = blockIdx.x * blockDim.x + threadIdx.x;
    if (e >= E) return;
    int s = src[e], d = dst[e];
    int p = atomicAdd(&cur[d], 1);
    edata[p] = make_int2(s, __float_as_int(dinv[s] * dinv[d]));
}

// ---------- encoder: h = elu(x @ enc_w + enc_b), x:[N,3] ----------
__global__ void k_enc(const float* __restrict__ x, const float* __restrict__ w,
                      const float* __restrict__ b, float* __restrict__ h, int N) {
    int idx = blockIdx.x * blockDim.x + threadIdx.x;   // over N*D4
    if (idx >= N * D4) return;
    int n = idx >> 5, c4 = idx & 31;
    const float4* w4 = (const float4*)w;
    float4 b4 = ((const float4*)b)[c4];
    float x0 = x[n * 3 + 0], x1 = x[n * 3 + 1], x2 = x[n * 3 + 2];
    float4 v = b4;
    v = f4fma(x0, w4[0 * D4 + c4], v);
    v = f4fma(x1, w4[1 * D4 + c4], v);
    v = f4fma(x2, w4[2 * D4 + c4], v);
    v.x = v.x > 0.f ? v.x : expm1f(v.x);
    v.y = v.y > 0.f ? v.y : expm1f(v.y);
    v.z = v.z > 0.f ? v.z : expm1f(v.z);
    v.w = v.w > 0.f ? v.w : expm1f(v.w);
    ((float4*)h)[idx] = v;
}

// ---------- per-layer LN-fold: W' = s_c * W, konst_j = sum_c o_c * W_cj ----------
// LN(x) @ W == x @ W' + konst.  lw==null -> identity (W'=W, konst=0).
__global__ void k_prep(const float* __restrict__ w, const float* __restrict__ lw,
                       const float* __restrict__ lb, const double* __restrict__ sums,
                       float* __restrict__ wout, float* __restrict__ konst, int N) {
    __shared__ float sc[D], of[D];
    float mu = 0.f, inv = 1.f;
    if (lw) {
        double M = (double)N * D;
        double m = sums[0] / M;
        double var = sums[1] / M - m * m;
        float sd = sqrtf(var > 0.0 ? (float)var : 0.f);
        inv = 1.f / (sd + 1e-5f);
        mu = (float)m;
    }
    for (int i = threadIdx.x; i < D; i += blockDim.x) {
        float l = lw ? lw[i] : 1.f;
        float s = inv * l;
        sc[i] = s;
        of[i] = (lw ? lb[i] : 0.f) - mu * s;
    }
    __syncthreads();
    if (blockIdx.x < 8) {
        int chunk = D * D / 8;   // 2048
        int base = blockIdx.x * chunk;
        for (int i = threadIdx.x; i < chunk; i += blockDim.x) {
            int idx = base + i;
            wout[idx] = sc[idx >> 7] * w[idx];
        }
    } else {
        for (int j = threadIdx.x; j < D; j += blockDim.x) {
            float acc = 0.f;
            for (int c = 0; c < D; ++c) acc = fmaf(of[c], w[c * D + j], acc);
            konst[j] = acc;
        }
    }
}

// ---------- dense matmul: out[N,128] = h[N,128] @ wp[128,128] + konst ----------
// 256 thr: 32 col-groups (4 cols) x 8 row-groups (8 rows each) => 64 rows/block
__launch_bounds__(256)
__global__ void k_mm(const float* __restrict__ h, const float* __restrict__ wp,
                     const float* __restrict__ konst, float* __restrict__ out, int N) {
    __shared__ float wl[D * D];          // 64 KB
    float4* wl4 = (float4*)wl;
    const float4* wg4 = (const float4*)wp;
    for (int i = threadIdx.x; i < D * D4; i += 256) wl4[i] = wg4[i];
    __syncthreads();

    int cg = threadIdx.x & 31;           // col-group: cols 4*cg..4*cg+3
    int rg = threadIdx.x >> 5;           // row-group 0..7
    int row0 = blockIdx.x * 64 + rg * 8;
    const float4* h4 = (const float4*)h;
    float4 k4 = ((const float4*)konst)[cg];

    float4 acc[8];
    #pragma unroll
    for (int r = 0; r < 8; ++r) acc[r] = k4;

    int nodes[8];
    #pragma unroll
    for (int r = 0; r < 8; ++r) { int nd = row0 + r; nodes[r] = nd < N ? nd : N - 1; }

    for (int kk = 0; kk < D; kk += 4) {
        float4 w0 = wl4[(kk + 0) * D4 + cg];
        float4 w1 = wl4[(kk + 1) * D4 + cg];
        float4 w2 = wl4[(kk + 2) * D4 + cg];
        float4 w3 = wl4[(kk + 3) * D4 + cg];
        #pragma unroll
        for (int r = 0; r < 8; ++r) {
            float4 hv = h4[(size_t)nodes[r] * D4 + (kk >> 2)];
            acc[r] = f4fma(hv.x, w0, acc[r]);
            acc[r] = f4fma(hv.y, w1, acc[r]);
            acc[r] = f4fma(hv.z, w2, acc[r]);
            acc[r] = f4fma(hv.w, w3, acc[r]);
        }
    }
    #pragma unroll
    for (int r = 0; r < 8; ++r) {
        int nd = row0 + r;
        if (nd < N) ((float4*)out)[(size_t)nd * D4 + cg] = acc[r];
    }
}

// ---------- channel-split CSR gather + self-loop + bias + relu + LN stats ----
// blockIdx.y = pass (CH passes, CPP=16 channels each -> 3.2 MB T-panel, fits
// per-XCD 4MB L2). 256 thr = 16 node-groups of 16 lanes; lane owns 1 channel.
__launch_bounds__(256)
__global__ void k_gather(const float* __restrict__ T, const int2* __restrict__ edata,
                         const int* __restrict__ rowptr, const float* __restrict__ dinv,
                         const float* __restrict__ bias, float* __restrict__ outA,
                         double* __restrict__ sums, int N) {
    int pass = blockIdx.y;
    int n = blockIdx.x * 16 + (threadIdx.x >> 4);
    int lane = threadIdx.x & 15;
    int c = pass * CPP + lane;            // this lane's channel
    float ls = 0.f, lq = 0.f;
    if (n < N) {
        int e0 = rowptr[n], e1 = rowptr[n + 1];
        float a0 = 0.f, a1 = 0.f, a2 = 0.f, a3 = 0.f;
        int e = e0;
        for (; e + 4 <= e1; e += 4) {
            int2 d0 = edata[e + 0];
            int2 d1 = edata[e + 1];
            int2 d2 = edata[e + 2];
            int2 d3 = edata[e + 3];
            float t0 = T[(size_t)d0.x * D + c];
            float t1 = T[(size_t)d1.x * D + c];
            float t2 = T[(size_t)d2.x * D + c];
            float t3 = T[(size_t)d3.x * D + c];
            a0 = fmaf(__int_as_float(d0.y), t0, a0);
            a1 = fmaf(__int_as_float(d1.y), t1, a1);
            a2 = fmaf(__int_as_float(d2.y), t2, a2);
            a3 = fmaf(__int_as_float(d3.y), t3, a3);
        }
        for (; e < e1; ++e) {
            int2 d = edata[e];
            a0 = fmaf(__int_as_float(d.y), T[(size_t)d.x * D + c], a0);
        }
        float acc = (a0 + a1) + (a2 + a3);
        float di = dinv[n];
        acc = fmaf(di * di, T[(size_t)n * D + c], acc);
        acc = fmaxf(acc + bias[c], 0.f);
        outA[(size_t)n * D + c] = acc;
        ls = acc;
        lq = acc * acc;
    }
    // wave64 reduce
    for (int off = 32; off; off >>= 1) {
        ls += __shfl_down(ls, off);
        lq += __shfl_down(lq, off);
    }
    __shared__ float ss[4], sq[4];
    int wid = threadIdx.x >> 6;
    if ((threadIdx.x & 63) == 0) { ss[wid] = ls; sq[wid] = lq; }
    __syncthreads();
    if (threadIdx.x == 0) {
        float S = ss[0] + ss[1] + ss[2] + ss[3];
        float Q = sq[0] + sq[1] + sq[2] + sq[3];
        atomicAdd(&sums[0], (double)S);
        atomicAdd(&sums[1], (double)Q);
    }
}

// ---------- global max pool per graph, applying final LN inline ----------
// 512 thr: channel c = tid&127, node-subset sub = tid>>7 (4-way)
__launch_bounds__(512)
__global__ void k_pool(const float* __restrict__ A, const int* __restrict__ batch,
                       const float* __restrict__ lw, const float* __restrict__ lb,
                       const double* __restrict__ sums, float* __restrict__ g, int N) {
    int gi = blockIdx.x;
    int lo = 0, hi = N;
    while (lo < hi) { int mid = (lo + hi) >> 1; if (batch[mid] < gi) lo = mid + 1; else hi = mid; }
    int start = lo;
    hi = N;
    while (lo < hi) { int mid = (lo + hi) >> 1; if (batch[mid] < gi + 1) lo = mid + 1; else hi = mid; }
    int end = lo;

    int c = threadIdx.x & 127, sub = threadIdx.x >> 7;
    double M = (double)N * D;
    double m_ = sums[0] / M;
    double var = sums[1] / M - m_ * m_;
    float sd = sqrtf(var > 0.0 ? (float)var : 0.f);
    float inv = 1.f / (sd + 1e-5f);
    float s = inv * lw[c];
    float o = lb[c] - (float)m_ * s;

    float mx = -FLT_MAX;
    for (int node = start + sub; node < end; node += 4)
        mx = fmaxf(mx, fmaf(A[(size_t)node * D + c], s, o));

    __shared__ float red[4][128];
    red[sub][c] = mx;
    __syncthreads();
    if (sub == 0) {
        mx = fmaxf(fmaxf(red[0][c], red[1][c]), fmaxf(red[2][c], red[3][c]));
        g[gi * D + c] = mx;
    }
}

// ---------- t = tanh(g @ fc_w + fc_b) ----------
__global__ void k_fc(const float* __restrict__ g, const float* __restrict__ w,
                     const float* __restrict__ b, float* __restrict__ t) {
    __shared__ float row[D];
    int gi = blockIdx.x, c = threadIdx.x;
    row[c] = g[gi * D + c];
    __syncthreads();
    float acc = b[c];
    for (int k = 0; k < D; ++k) acc = fmaf(row[k], w[k * D + c], acc);
    t[gi * D + c] = tanhf(acc);
}

// ---------- out = t @ pred_w + pred_b ----------
__global__ void k_pred(const float* __restrict__ t, const float* __restrict__ w,
                       const float* __restrict__ b, float* __restrict__ out, int total) {
    int i = blockIdx.x * blockDim.x + threadIdx.x;
    if (i >= total) return;
    int gi = i / 10, j = i % 10;
    float acc = b[j];
    for (int k = 0; k < D; ++k) acc = fmaf(t[gi * D + k], w[k * 10 + j], acc);
    out[i] = acc;
}

extern "C" void kernel_launch(void* const* d_in, const int* in_sizes, int n_in,
                              void* d_out, int out_size, void* d_ws, size_t ws_size,
                              hipStream_t stream) {
    const float* x      = (const float*)d_in[0];
    const int*   src    = (const int*)d_in[1];
    const int*   dst    = (const int*)d_in[2];
    const int*   batch  = (const int*)d_in[3];
    const float* enc_w  = (const float*)d_in[4];
    const float* enc_b  = (const float*)d_in[5];
    const float* fc_w   = (const float*)d_in[6];
    const float* fc_b   = (const float*)d_in[7];
    const float* pred_w = (const float*)d_in[8];
    const float* pred_b = (const float*)d_in[9];

    int N = in_sizes[0] / 3;
    int E = in_sizes[1];
    int G = out_size / 10;

    char* ws = (char*)d_ws;
    size_t off = 0;
    auto align512 = [](size_t v) { return (v + 511) / 512 * 512; };
    float* dinv   = (float*)(ws + off); off += align512((size_t)N * 4);
    int*   cnt    = (int*)(ws + off);   off += align512((size_t)N * 4);
    int*   rowptr = (int*)(ws + off);   off += align512(((size_t)N + 1) * 4);
    int*   cur    = (int*)(ws + off);   off += align512((size_t)N * 4);
    int2*  edata  = (int2*)(ws + off);  off += align512((size_t)E * 8);
    float* A      = (float*)(ws + off); off += (size_t)N * D * 4;
    float* T      = (float*)(ws + off); off += (size_t)N * D * 4;
    double* sums  = (double*)(ws + off); off += 512;
    float* wp     = (float*)(ws + off); off += (size_t)D * D * 4;
    float* konst  = (float*)(ws + off); off += align512((size_t)D * 4);
    float* gmax   = (float*)(ws + off); off += (size_t)G * D * 4;
    float* tb     = (float*)(ws + off); off += (size_t)G * D * 4;

    // ---- CSR build (per launch; inputs restored every call) ----
    hipMemsetAsync(cnt, 0, (size_t)N * 4, stream);
    k_count<<<(E + 255) / 256, 256, 0, stream>>>(dst, cnt, E);
    k_dinv<<<(N + 255) / 256, 256, 0, stream>>>(cnt, dinv, N);
    k_scan<<<1, 1024, 0, stream>>>(cnt, rowptr, cur, N);
    k_fill<<<(E + 255) / 256, 256, 0, stream>>>(src, dst, dinv, cur, edata, E);

    // ---- encoder ----
    int tot4 = N * D4;
    k_enc<<<(tot4 + 255) / 256, 256, 0, stream>>>(x, enc_w, enc_b, A, N);

    // ---- 4 GCN layers (LN of layer L-1 folded into layer L's weights) ----
    dim3 ggrid((N + 15) / 16, CH);
    for (int L = 0; L < 4; ++L) {
        const float* w  = (const float*)d_in[10 + 4 * L];
        const float* b  = (const float*)d_in[11 + 4 * L];
        const float* lwp = L ? (const float*)d_in[12 + 4 * (L - 1)] : nullptr;
        const float* lbp = L ? (const float*)d_in[13 + 4 * (L - 1)] : nullptr;
        k_prep<<<9, 256, 0, stream>>>(w, lwp, lbp, sums, wp, konst, N);
        k_mm<<<(N + 63) / 64, 256, 0, stream>>>(A, wp, konst, T, N);
        hipMemsetAsync(sums, 0, 16, stream);
        k_gather<<<ggrid, 256, 0, stream>>>(T, edata, rowptr, dinv, b, A, sums, N);
    }

    // ---- final LN applied inside pool ----
    const float* lw3 = (const float*)d_in[12 + 4 * 3];
    const float* lb3 = (const float*)d_in[13 + 4 * 3];
    k_pool<<<G, 512, 0, stream>>>(A, batch, lw3, lb3, sums, gmax, N);
    k_fc<<<G, D, 0, stream>>>(gmax, fc_w, fc_b, tb);
    k_pred<<<(G * 10 + 255) / 256, 256, 0, stream>>>(tb, pred_w, pred_b, (float*)d_out, G * 10);
}

// Round 7
// 1191.182 us; speedup vs baseline: 2.5138x; 2.5138x over previous
//
#include <hip/hip_runtime.h>
#include <cfloat>
#include <cmath>

#define D 128
#define D4 32   // D/4 float4s per row
#define D8 32   // D/4 ushort4s per bf16 row (4 ch per ushort4)

// ---------- helpers ----------
__device__ __forceinline__ float4 f4fma(float s, float4 a, float4 acc) {
    acc.x = fmaf(s, a.x, acc.x);
    acc.y = fmaf(s, a.y, acc.y);
    acc.z = fmaf(s, a.z, acc.z);
    acc.w = fmaf(s, a.w, acc.w);
    return acc;
}

__device__ __forceinline__ unsigned short f2bf(float x) {
    unsigned int b = __float_as_uint(x);
    unsigned int r = (b + 0x7FFFu + ((b >> 16) & 1u)) >> 16;   // RNE
    return (unsigned short)r;
}

__device__ __forceinline__ float bf2f(unsigned short u) {
    return __uint_as_float(((unsigned int)u) << 16);
}

__device__ __forceinline__ float4 bf4_to_f4(ushort4 u) {
    return make_float4(bf2f(u.x), bf2f(u.y), bf2f(u.z), bf2f(u.w));
}

// ---------- degree count (int) ----------
__global__ void k_count(const int* __restrict__ dst, int* __restrict__ cnt, int E) {
    int i = blockIdx.x * blockDim.x + threadIdx.x;
    if (i < E) atomicAdd(&cnt[dst[i]], 1);
}

__global__ void k_dinv(const int* __restrict__ cnt, float* __restrict__ dinv, int N) {
    int i = blockIdx.x * blockDim.x + threadIdx.x;
    if (i < N) dinv[i] = 1.0f / sqrtf((float)cnt[i] + 1.0f);  // +1 = self-loop
}

// ---------- exclusive scan of cnt -> rowptr (single block, 1024 thr) ----------
__global__ __launch_bounds__(1024)
void k_scan(const int* __restrict__ cnt, int* __restrict__ rowptr,
            int* __restrict__ cur, int N) {
    __shared__ int part[1024];
    int t = threadIdx.x;
    int chunk = (N + 1023) / 1024;
    int begin = t * chunk;
    int end = begin + chunk; if (end > N) end = N;
    int s = 0;
    for (int i = begin; i < end; ++i) s += cnt[i];
    part[t] = s;
    __syncthreads();
    for (int off = 1; off < 1024; off <<= 1) {
        int v = (t >= off) ? part[t - off] : 0;
        __syncthreads();
        part[t] += v;
        __syncthreads();
    }
    int run = (t == 0) ? 0 : part[t - 1];
    for (int i = begin; i < end; ++i) {
        rowptr[i] = run; cur[i] = run;
        run += cnt[i];
    }
    if (t == 1023) rowptr[N] = part[1023];
}

// ---------- fill CSR edge data: (src, norm) sorted by dst ----------
__global__ void k_fill(const int* __restrict__ src, const int* __restrict__ dst,
                       const float* __restrict__ dinv, int* __restrict__ cur,
                       int2* __restrict__ edata, int E) {
    int e = blockIdx.x * blockDim.x + threadIdx.x;
    if (e >= E) return;
    int s = src[e], d = dst[e];
    int p = atomicAdd(&cur[d], 1);
    edata[p] = make_int2(s, __float_as_int(dinv[s] * dinv[d]));
}

// ---------- encoder: h = elu(x @ enc_w + enc_b), x:[N,3] ----------
__global__ void k_enc(const float* __restrict__ x, const float* __restrict__ w,
                      const float* __restrict__ b, float* __restrict__ h, int N) {
    int idx = blockIdx.x * blockDim.x + threadIdx.x;   // over N*D4
    if (idx >= N * D4) return;
    int n = idx >> 5, c4 = idx & 31;
    const float4* w4 = (const float4*)w;
    float4 b4 = ((const float4*)b)[c4];
    float x0 = x[n * 3 + 0], x1 = x[n * 3 + 1], x2 = x[n * 3 + 2];
    float4 v = b4;
    v = f4fma(x0, w4[0 * D4 + c4], v);
    v = f4fma(x1, w4[1 * D4 + c4], v);
    v = f4fma(x2, w4[2 * D4 + c4], v);
    v.x = v.x > 0.f ? v.x : expm1f(v.x);
    v.y = v.y > 0.f ? v.y : expm1f(v.y);
    v.z = v.z > 0.f ? v.z : expm1f(v.z);
    v.w = v.w > 0.f ? v.w : expm1f(v.w);
    ((float4*)h)[idx] = v;
}

// ---------- per-layer LN-fold: W' = s_c * W, konst_j = sum_c o_c * W_cj ----------
// LN(x) @ W == x @ W' + konst.  lw==null -> identity (W'=W, konst=0).
__global__ void k_prep(const float* __restrict__ w, const float* __restrict__ lw,
                       const float* __restrict__ lb, const double* __restrict__ sums,
                       float* __restrict__ wout, float* __restrict__ konst, int N) {
    __shared__ float sc[D], of[D];
    float mu = 0.f, inv = 1.f;
    if (lw) {
        double M = (double)N * D;
        double m = sums[0] / M;
        double var = sums[1] / M - m * m;
        float sd = sqrtf(var > 0.0 ? (float)var : 0.f);
        inv = 1.f / (sd + 1e-5f);
        mu = (float)m;
    }
    for (int i = threadIdx.x; i < D; i += blockDim.x) {
        float l = lw ? lw[i] : 1.f;
        float s = inv * l;
        sc[i] = s;
        of[i] = (lw ? lb[i] : 0.f) - mu * s;
    }
    __syncthreads();
    if (blockIdx.x < 8) {
        int chunk = D * D / 8;   // 2048
        int base = blockIdx.x * chunk;
        for (int i = threadIdx.x; i < chunk; i += blockDim.x) {
            int idx = base + i;
            wout[idx] = sc[idx >> 7] * w[idx];
        }
    } else {
        for (int j = threadIdx.x; j < D; j += blockDim.x) {
            float acc = 0.f;
            for (int c = 0; c < D; ++c) acc = fmaf(of[c], w[c * D + j], acc);
            konst[j] = acc;
        }
    }
}

// ---------- dense matmul: T[N,128](bf16) = h[N,128] @ wp[128,128] + konst ----
// 256 thr: 32 col-groups (4 cols) x 8 row-groups (8 rows each) => 64 rows/block
__launch_bounds__(256)
__global__ void k_mm(const float* __restrict__ h, const float* __restrict__ wp,
                     const float* __restrict__ konst, unsigned short* __restrict__ out,
                     int N) {
    __shared__ float wl[D * D];          // 64 KB
    float4* wl4 = (float4*)wl;
    const float4* wg4 = (const float4*)wp;
    for (int i = threadIdx.x; i < D * D4; i += 256) wl4[i] = wg4[i];
    __syncthreads();

    int cg = threadIdx.x & 31;           // col-group: cols 4*cg..4*cg+3
    int rg = threadIdx.x >> 5;           // row-group 0..7
    int row0 = blockIdx.x * 64 + rg * 8;
    const float4* h4 = (const float4*)h;
    float4 k4 = ((const float4*)konst)[cg];

    float4 acc[8];
    #pragma unroll
    for (int r = 0; r < 8; ++r) acc[r] = k4;

    int nodes[8];
    #pragma unroll
    for (int r = 0; r < 8; ++r) { int nd = row0 + r; nodes[r] = nd < N ? nd : N - 1; }

    for (int kk = 0; kk < D; kk += 4) {
        float4 w0 = wl4[(kk + 0) * D4 + cg];
        float4 w1 = wl4[(kk + 1) * D4 + cg];
        float4 w2 = wl4[(kk + 2) * D4 + cg];
        float4 w3 = wl4[(kk + 3) * D4 + cg];
        #pragma unroll
        for (int r = 0; r < 8; ++r) {
            float4 hv = h4[(size_t)nodes[r] * D4 + (kk >> 2)];
            acc[r] = f4fma(hv.x, w0, acc[r]);
            acc[r] = f4fma(hv.y, w1, acc[r]);
            acc[r] = f4fma(hv.z, w2, acc[r]);
            acc[r] = f4fma(hv.w, w3, acc[r]);
        }
    }
    #pragma unroll
    for (int r = 0; r < 8; ++r) {
        int nd = row0 + r;
        if (nd < N) {
            ushort4 o;
            o.x = f2bf(acc[r].x); o.y = f2bf(acc[r].y);
            o.z = f2bf(acc[r].z); o.w = f2bf(acc[r].w);
            ((ushort4*)out)[(size_t)nd * D8 + cg] = o;
        }
    }
}

// ---------- CSR gather (bf16 T) + self-loop + bias + relu + LN stats ----------
// 8 nodes per 256-thr block; 32 lanes per node (ushort4 = 4 bf16 ch per lane)
__launch_bounds__(256)
__global__ void k_gather(const unsigned short* __restrict__ T,
                         const int2* __restrict__ edata,
                         const int* __restrict__ rowptr, const float* __restrict__ dinv,
                         const float* __restrict__ bias, float* __restrict__ outA,
                         double* __restrict__ sums, int N) {
    int n = blockIdx.x * 8 + (threadIdx.x >> 5);
    int lane = threadIdx.x & 31;
    const ushort4* T4 = (const ushort4*)T;
    float ls = 0.f, lq = 0.f;
    if (n < N) {
        int e0 = rowptr[n], e1 = rowptr[n + 1];
        float4 a0 = make_float4(0.f, 0.f, 0.f, 0.f);
        float4 a1 = a0, a2 = a0, a3 = a0;
        int e = e0;
        for (; e + 4 <= e1; e += 4) {
            int2 d0 = edata[e + 0];
            int2 d1 = edata[e + 1];
            int2 d2 = edata[e + 2];
            int2 d3 = edata[e + 3];
            ushort4 t0 = T4[(size_t)d0.x * D8 + lane];
            ushort4 t1 = T4[(size_t)d1.x * D8 + lane];
            ushort4 t2 = T4[(size_t)d2.x * D8 + lane];
            ushort4 t3 = T4[(size_t)d3.x * D8 + lane];
            a0 = f4fma(__int_as_float(d0.y), bf4_to_f4(t0), a0);
            a1 = f4fma(__int_as_float(d1.y), bf4_to_f4(t1), a1);
            a2 = f4fma(__int_as_float(d2.y), bf4_to_f4(t2), a2);
            a3 = f4fma(__int_as_float(d3.y), bf4_to_f4(t3), a3);
        }
        for (; e < e1; ++e) {
            int2 d = edata[e];
            a0 = f4fma(__int_as_float(d.y), bf4_to_f4(T4[(size_t)d.x * D8 + lane]), a0);
        }
        a0.x += a1.x; a0.y += a1.y; a0.z += a1.z; a0.w += a1.w;
        a2.x += a3.x; a2.y += a3.y; a2.z += a3.z; a2.w += a3.w;
        float4 acc;
        acc.x = a0.x + a2.x; acc.y = a0.y + a2.y;
        acc.z = a0.z + a2.z; acc.w = a0.w + a2.w;
        float di = dinv[n];
        acc = f4fma(di * di, bf4_to_f4(T4[(size_t)n * D8 + lane]), acc);
        float4 b4 = ((const float4*)bias)[lane];
        acc.x = fmaxf(acc.x + b4.x, 0.f);
        acc.y = fmaxf(acc.y + b4.y, 0.f);
        acc.z = fmaxf(acc.z + b4.z, 0.f);
        acc.w = fmaxf(acc.w + b4.w, 0.f);
        ((float4*)outA)[(size_t)n * D4 + lane] = acc;
        ls = acc.x + acc.y + acc.z + acc.w;
        lq = acc.x * acc.x + acc.y * acc.y + acc.z * acc.z + acc.w * acc.w;
    }
    // wave64 reduce
    for (int off = 32; off; off >>= 1) {
        ls += __shfl_down(ls, off);
        lq += __shfl_down(lq, off);
    }
    __shared__ float ss[4], sq[4];
    int wid = threadIdx.x >> 6;
    if ((threadIdx.x & 63) == 0) { ss[wid] = ls; sq[wid] = lq; }
    __syncthreads();
    if (threadIdx.x == 0) {
        float S = ss[0] + ss[1] + ss[2] + ss[3];
        float Q = sq[0] + sq[1] + sq[2] + sq[3];
        atomicAdd(&sums[0], (double)S);
        atomicAdd(&sums[1], (double)Q);
    }
}

// ---------- global max pool per graph, applying final LN inline ----------
// 512 thr: channel c = tid&127, node-subset sub = tid>>7 (4-way)
__launch_bounds__(512)
__global__ void k_pool(const float* __restrict__ A, const int* __restrict__ batch,
                       const float* __restrict__ lw, const float* __restrict__ lb,
                       const double* __restrict__ sums, float* __restrict__ g, int N) {
    int gi = blockIdx.x;
    int lo = 0, hi = N;
    while (lo < hi) { int mid = (lo + hi) >> 1; if (batch[mid] < gi) lo = mid + 1; else hi = mid; }
    int start = lo;
    hi = N;
    while (lo < hi) { int mid = (lo + hi) >> 1; if (batch[mid] < gi + 1) lo = mid + 1; else hi = mid; }
    int end = lo;

    int c = threadIdx.x & 127, sub = threadIdx.x >> 7;
    double M = (double)N * D;
    double m_ = sums[0] / M;
    double var = sums[1] / M - m_ * m_;
    float sd = sqrtf(var > 0.0 ? (float)var : 0.f);
    float inv = 1.f / (sd + 1e-5f);
    float s = inv * lw[c];
    float o = lb[c] - (float)m_ * s;

    float mx = -FLT_MAX;
    for (int node = start + sub; node < end; node += 4)
        mx = fmaxf(mx, fmaf(A[(size_t)node * D + c], s, o));

    __shared__ float red[4][128];
    red[sub][c] = mx;
    __syncthreads();
    if (sub == 0) {
        mx = fmaxf(fmaxf(red[0][c], red[1][c]), fmaxf(red[2][c], red[3][c]));
        g[gi * D + c] = mx;
    }
}

// ---------- t = tanh(g @ fc_w + fc_b) ----------
__global__ void k_fc(const float* __restrict__ g, const float* __restrict__ w,
                     const float* __restrict__ b, float* __restrict__ t) {
    __shared__ float row[D];
    int gi = blockIdx.x, c = threadIdx.x;
    row[c] = g[gi * D + c];
    __syncthreads();
    float acc = b[c];
    for (int k = 0; k < D; ++k) acc = fmaf(row[k], w[k * D + c], acc);
    t[gi * D + c] = tanhf(acc);
}

// ---------- out = t @ pred_w + pred_b ----------
__global__ void k_pred(const float* __restrict__ t, const float* __restrict__ w,
                       const float* __restrict__ b, float* __restrict__ out, int total) {
    int i = blockIdx.x * blockDim.x + threadIdx.x;
    if (i >= total) return;
    int gi = i / 10, j = i % 10;
    float acc = b[j];
    for (int k = 0; k < D; ++k) acc = fmaf(t[gi * D + k], w[k * 10 + j], acc);
    out[i] = acc;
}

extern "C" void kernel_launch(void* const* d_in, const int* in_sizes, int n_in,
                              void* d_out, int out_size, void* d_ws, size_t ws_size,
                              hipStream_t stream) {
    const float* x      = (const float*)d_in[0];
    const int*   src    = (const int*)d_in[1];
    const int*   dst    = (const int*)d_in[2];
    const int*   batch  = (const int*)d_in[3];
    const float* enc_w  = (const float*)d_in[4];
    const float* enc_b  = (const float*)d_in[5];
    const float* fc_w   = (const float*)d_in[6];
    const float* fc_b   = (const float*)d_in[7];
    const float* pred_w = (const float*)d_in[8];
    const float* pred_b = (const float*)d_in[9];

    int N = in_sizes[0] / 3;
    int E = in_sizes[1];
    int G = out_size / 10;

    char* ws = (char*)d_ws;
    size_t off = 0;
    auto align512 = [](size_t v) { return (v + 511) / 512 * 512; };
    float* dinv   = (float*)(ws + off); off += align512((size_t)N * 4);
    int*   cnt    = (int*)(ws + off);   off += align512((size_t)N * 4);
    int*   rowptr = (int*)(ws + off);   off += align512(((size_t)N + 1) * 4);
    int*   cur    = (int*)(ws + off);   off += align512((size_t)N * 4);
    int2*  edata  = (int2*)(ws + off);  off += align512((size_t)E * 8);
    float* A      = (float*)(ws + off); off += (size_t)N * D * 4;
    unsigned short* T = (unsigned short*)(ws + off); off += align512((size_t)N * D * 2);
    double* sums  = (double*)(ws + off); off += 512;
    float* wp     = (float*)(ws + off); off += (size_t)D * D * 4;
    float* konst  = (float*)(ws + off); off += align512((size_t)D * 4);
    float* gmax   = (float*)(ws + off); off += (size_t)G * D * 4;
    float* tb     = (float*)(ws + off); off += (size_t)G * D * 4;

    // ---- CSR build (per launch; inputs restored every call) ----
    hipMemsetAsync(cnt, 0, (size_t)N * 4, stream);
    k_count<<<(E + 255) / 256, 256, 0, stream>>>(dst, cnt, E);
    k_dinv<<<(N + 255) / 256, 256, 0, stream>>>(cnt, dinv, N);
    k_scan<<<1, 1024, 0, stream>>>(cnt, rowptr, cur, N);
    k_fill<<<(E + 255) / 256, 256, 0, stream>>>(src, dst, dinv, cur, edata, E);

    // ---- encoder ----
    int tot4 = N * D4;
    k_enc<<<(tot4 + 255) / 256, 256, 0, stream>>>(x, enc_w, enc_b, A, N);

    // ---- 4 GCN layers (LN of layer L-1 folded into layer L's weights) ----
    for (int L = 0; L < 4; ++L) {
        const float* w  = (const float*)d_in[10 + 4 * L];
        const float* b  = (const float*)d_in[11 + 4 * L];
        const float* lwp = L ? (const float*)d_in[12 + 4 * (L - 1)] : nullptr;
        const float* lbp = L ? (const float*)d_in[13 + 4 * (L - 1)] : nullptr;
        k_prep<<<9, 256, 0, stream>>>(w, lwp, lbp, sums, wp, konst, N);
        k_mm<<<(N + 63) / 64, 256, 0, stream>>>(A, wp, konst, T, N);
        hipMemsetAsync(sums, 0, 16, stream);
        k_gather<<<(N + 7) / 8, 256, 0, stream>>>(T, edata, rowptr, dinv, b, A, sums, N);
    }

    // ---- final LN applied inside pool ----
    const float* lw3 = (const float*)d_in[12 + 4 * 3];
    const float* lb3 = (const float*)d_in[13 + 4 * 3];
    k_pool<<<G, 512, 0, stream>>>(A, batch, lw3, lb3, sums, gmax, N);
    k_fc<<<G, D, 0, stream>>>(gmax, fc_w, fc_b, tb);
    k_pred<<<(G * 10 + 255) / 256, 256, 0, stream>>>(tb, pred_w, pred_b, (float*)d_out, G * 10);
}